// Round 1
// 955.474 us; speedup vs baseline: 1.1912x; 1.1912x over previous
//
#include <hip/hip_runtime.h>

typedef unsigned short u16;
typedef unsigned int   u32;
typedef short short8 __attribute__((ext_vector_type(8)));
typedef _Float16 half8 __attribute__((ext_vector_type(8)));
typedef float f32x4  __attribute__((ext_vector_type(4)));

#define NN 768
#define N2 (768*768)

__device__ __forceinline__ u16 f2b(float f) {           // fp32 -> bf16 RNE
  u32 u = __float_as_uint(f);
  return (u16)((u + 0x7FFFu + ((u >> 16) & 1u)) >> 16);
}
__device__ __forceinline__ float b2f(u16 h) { return __uint_as_float(((u32)h) << 16); }
__device__ __forceinline__ u16 f2h(float f) {           // fp32 -> fp16 RNE (v_cvt_f16_f32)
  _Float16 h = (_Float16)f;
  return __builtin_bit_cast(u16, h);
}
__device__ __forceinline__ float h2f(u16 h) { return (float)__builtin_bit_cast(_Float16, h); }

// async global->LDS, 16B per lane; LDS dest = wave-uniform base + lane*16
__device__ __forceinline__ void gl_lds16(const void* g, void* lds) {
  __builtin_amdgcn_global_load_lds((__attribute__((address_space(1))) void*)(void*)g,
                                   (__attribute__((address_space(3))) void*)lds, 16, 0, 0);
}

// swizzled frag loads from LDS: rows 256B / 128B; 16B chunk slot = chunk ^ (row&7)
__device__ __forceinline__ short8 frag256(const u16* base, int row, int k) {
  int c = k >> 3;
  int slot = ((c & 7) ^ (row & 7)) | (c & 8);
  return *(const short8*)(base + row*128 + slot*8);
}
__device__ __forceinline__ short8 frag128(const u16* base, int row, int k) {
  int c = k >> 3;
  int slot = (c ^ row) & 7;
  return *(const short8*)(base + row*64 + slot*8);
}
// fragment-major global weight read: layout [k>>3][row][8], produced by k0
__device__ __forceinline__ short8 fragG(const u16* wg, int row, int k) {
  return *(const short8*)(wg + (((k >> 3)*128) + row)*8);
}
__device__ __forceinline__ f32x4 mfma_bf(short8 a, short8 b, f32x4 c) {
  return __builtin_amdgcn_mfma_f32_16x16x32_bf16(a, b, c, 0, 0, 0);
}
__device__ __forceinline__ f32x4 mfma_h(short8 a, short8 b, f32x4 c) {
  return __builtin_amdgcn_mfma_f32_16x16x32_f16(
      __builtin_bit_cast(half8, a), __builtin_bit_cast(half8, b), c, 0, 0, 0);
}
__device__ __forceinline__ float sigm(float x) {
  return __builtin_amdgcn_rcpf(1.f + __expf(-x));      // no slow f32 divide
}

// ---------------- k0: weights fp32 -> fp16, fragment-major [c][row][8] ----------------
__global__ void k0_cvt(const float* __restrict__ w0, const float* __restrict__ w1,
                       const float* __restrict__ w2, const float* __restrict__ w3,
                       const float* __restrict__ w4, const float* __restrict__ w5,
                       u16* __restrict__ dst) {
  int t = blockIdx.x*256 + threadIdx.x;     // 6 * 2048 chunk-threads
  int m = t >> 11, o = t & 2047;
  int h = o >> 4, c = o & 15;               // row h, k-chunk c
  const float* s;
  switch (m) { case 0: s=w0; break; case 1: s=w1; break; case 2: s=w2; break;
               case 3: s=w3; break; case 4: s=w4; break; default: s=w5; }
  const float* p = s + h*128 + c*8;
  float4 f0 = *(const float4*)p;
  float4 f1 = *(const float4*)(p + 4);
  short8 r;
  r[0]=(short)f2h(f0.x); r[1]=(short)f2h(f0.y); r[2]=(short)f2h(f0.z); r[3]=(short)f2h(f0.w);
  r[4]=(short)f2h(f1.x); r[5]=(short)f2h(f1.y); r[6]=(short)f2h(f1.z); r[7]=(short)f2h(f1.w);
  *(short8*)(dst + (size_t)m*16384 + (size_t)(c*128 + h)*8) = r;
}

// ---------------- k1: LN + 5 projections + transpose ----------------
// wbf order: 0=w_left_gate 1=w_left 2=w_right_gate 3=w_right 4=w_out_gate 5=w_out
__global__ __launch_bounds__(256, 2) void k1_proj(
    const float* __restrict__ x, const float* __restrict__ mask,
    const float* __restrict__ nw, const float* __restrict__ nb,
    const u16* __restrict__ wbf,
    u16* __restrict__ left_t, u16* __restrict__ right_t, u16* __restrict__ gate_t)
{
  __shared__ __align__(16) u16 As[128*128];   // xn tile (fp16, swizzled)
  __shared__ __align__(16) u16 Ts[128*128];   // transpose buffer
  __shared__ float maskL[128];

  const int tid = threadIdx.x, w = tid>>6, l = tid&63;
  const long r0 = (long)blockIdx.x * 128;     // 128 rows (i,k) per block

  if (tid < 128) maskL[tid] = mask[r0 + tid];

  { // LayerNorm: 16 lanes per row, 4 rows in flight per wave
    const int g = l >> 4, sl = l & 15;
    const float4 nw0 = *(const float4*)(nw + sl*8);
    const float4 nw1 = *(const float4*)(nw + sl*8 + 4);
    const float4 nb0 = *(const float4*)(nb + sl*8);
    const float4 nb1 = *(const float4*)(nb + sl*8 + 4);
    #pragma unroll
    for (int it = 0; it < 8; ++it) {
      int row = w*32 + it*4 + g;
      const float* xp = x + (r0 + row)*128 + sl*8;
      float4 v0 = *(const float4*)xp;
      float4 v1 = *(const float4*)(xp + 4);
      float s  = (v0.x+v0.y) + (v0.z+v0.w) + (v1.x+v1.y) + (v1.z+v1.w);
      float s2 = (v0.x*v0.x+v0.y*v0.y) + (v0.z*v0.z+v0.w*v0.w)
               + (v1.x*v1.x+v1.y*v1.y) + (v1.z*v1.z+v1.w*v1.w);
      #pragma unroll
      for (int off = 1; off < 16; off <<= 1) {   // 16-lane group reduce
        s  += __shfl_xor(s,  off, 64);
        s2 += __shfl_xor(s2, off, 64);
      }
      float mu = s * 0.0078125f;
      float rs = __builtin_amdgcn_rsqf(s2 * 0.0078125f - mu*mu + 1e-5f);
      short8 rr;
      rr[0] = (short)f2h((v0.x-mu)*rs*nw0.x + nb0.x);
      rr[1] = (short)f2h((v0.y-mu)*rs*nw0.y + nb0.y);
      rr[2] = (short)f2h((v0.z-mu)*rs*nw0.z + nb0.z);
      rr[3] = (short)f2h((v0.w-mu)*rs*nw0.w + nb0.w);
      rr[4] = (short)f2h((v1.x-mu)*rs*nw1.x + nb1.x);
      rr[5] = (short)f2h((v1.y-mu)*rs*nw1.y + nb1.y);
      rr[6] = (short)f2h((v1.z-mu)*rs*nw1.z + nb1.z);
      rr[7] = (short)f2h((v1.w-mu)*rs*nw1.w + nb1.w);
      int slot = ((sl&7)^(row&7)) | (sl&8);
      *(short8*)(As + row*128 + slot*8) = rr;
    }
  }
  __syncthreads();

  const int q = l>>4, mm = l&15;
  const int wi = w & 1, wj = w >> 1;          // wave tile: 64 rows x 64 cols

  float mk[4][4];
  #pragma unroll
  for (int a2 = 0; a2 < 4; ++a2)
    #pragma unroll
    for (int r = 0; r < 4; ++r)
      mk[a2][r] = maskL[wi*64 + a2*16 + q*4 + r];

  // pair pass: gate proj (+ optional main proj), B-fragments straight from L2
  auto pairPass = [&](const u16* wG, const u16* wM, bool hasMain, bool fp16out, u16* dst) {
    f32x4 accG[4][4], accM[4][4];
    #pragma unroll
    for (int a2 = 0; a2 < 4; ++a2)
      #pragma unroll
      for (int b2 = 0; b2 < 4; ++b2) {
        accG[a2][b2] = (f32x4){0.f,0.f,0.f,0.f};
        accM[a2][b2] = (f32x4){0.f,0.f,0.f,0.f};
      }
    #pragma unroll
    for (int ks = 0; ks < 4; ++ks) {
      int k = ks*32 + q*8;
      short8 a[4];
      #pragma unroll
      for (int a2 = 0; a2 < 4; ++a2) a[a2] = frag256(As, wi*64 + a2*16 + mm, k);
      #pragma unroll
      for (int b2 = 0; b2 < 4; ++b2) {
        short8 bg = fragG(wG, wj*64 + b2*16 + mm, k);
        #pragma unroll
        for (int a2 = 0; a2 < 4; ++a2) accG[a2][b2] = mfma_h(a[a2], bg, accG[a2][b2]);
        if (hasMain) {
          short8 bm = fragG(wM, wj*64 + b2*16 + mm, k);
          #pragma unroll
          for (int a2 = 0; a2 < 4; ++a2) accM[a2][b2] = mfma_h(a[a2], bm, accM[a2][b2]);
        }
      }
    }
    #pragma unroll
    for (int a2 = 0; a2 < 4; ++a2)
      #pragma unroll
      for (int b2 = 0; b2 < 4; ++b2)
        #pragma unroll
        for (int r = 0; r < 4; ++r)
          accG[a2][b2][r] = sigm(accG[a2][b2][r]);
    if (hasMain) {
      #pragma unroll
      for (int a2 = 0; a2 < 4; ++a2)
        #pragma unroll
        for (int b2 = 0; b2 < 4; ++b2)
          #pragma unroll
          for (int r = 0; r < 4; ++r)
            accM[a2][b2][r] *= mk[a2][r] * accG[a2][b2][r];
    }
    f32x4 (*res)[4] = hasMain ? accM : accG;
    // scatter C (rows=k, cols=d) into Ts as T[d][k] (256B rows, swizzled)
    #pragma unroll
    for (int a2 = 0; a2 < 4; ++a2)
      #pragma unroll
      for (int b2 = 0; b2 < 4; ++b2) {
        int kl = wi*64 + a2*16 + q*4;
        int d  = wj*64 + b2*16 + mm;
        int c = kl >> 3, slot = ((c&7)^(d&7)) | (c&8);
        f32x4 t = res[a2][b2];
        u32 p0, p1;
        if (fp16out) {
          p0 = (u32)f2h(t[0]) | ((u32)f2h(t[1])<<16);
          p1 = (u32)f2h(t[2]) | ((u32)f2h(t[3])<<16);
        } else {
          p0 = (u32)f2b(t[0]) | ((u32)f2b(t[1])<<16);
          p1 = (u32)f2b(t[2]) | ((u32)f2b(t[3])<<16);
        }
        *(uint2*)(Ts + d*128 + slot*8 + (kl&7)) = make_uint2(p0, p1);
      }
    __syncthreads();
    // cooperative coalesced store: wave w -> d rows w*32..w*32+31, 256B per row
    #pragma unroll
    for (int g2 = 0; g2 < 2; ++g2) {
      int d = w*32 + g2*16 + (l>>2);
      #pragma unroll
      for (int p = 0; p < 4; ++p) {
        int cc = p*4 + (l&3);
        int slot = ((cc&7)^(d&7)) | (cc&8);
        uint4 vv = *(const uint4*)(Ts + d*128 + slot*8);
        *(uint4*)(dst + (long)d*N2 + r0 + cc*8) = vv;
      }
    }
    __syncthreads();
  };

  pairPass(wbf + 0*16384, wbf + 1*16384, true,  false, left_t);
  pairPass(wbf + 2*16384, wbf + 3*16384, true,  false, right_t);
  pairPass(wbf + 4*16384, wbf + 4*16384, false, true,  gate_t);
}

// ---------------- k2: 128 batched 768^3 NT-GEMMs (bf16, ref semantics) ----------------
__global__ __launch_bounds__(256, 2) void k2_gemm(
    const u16* __restrict__ left_t, const u16* __restrict__ right_t, u16* __restrict__ out_ws)
{
  __shared__ __align__(16) u16 As[128*64];
  __shared__ __align__(16) u16 Bs[128*64];
  const int tid = threadIdx.x, w = tid>>6, l = tid&63;
  int bid0 = blockIdx.x;
  int bid = (bid0 & 7)*576 + (bid0 >> 3);     // bijective XCD swizzle: 16 d-channels per XCD
  int d = bid / 36, t36 = bid % 36;
  int it = t36 / 6, jt = t36 % 6;
  const u16* Lb = left_t  + (long)d*N2 + (long)it*128*NN;
  const u16* Rb = right_t + (long)d*N2 + (long)jt*128*NN;
  const int wi = w & 1, wj = w >> 1;
  const int q = l>>4, mm = l&15;
  const int rloc = l>>3, sv = l&7;
  f32x4 acc[4][4];
  #pragma unroll
  for (int a2 = 0; a2 < 4; ++a2)
    #pragma unroll
    for (int b2 = 0; b2 < 4; ++b2) acc[a2][b2] = (f32x4){0.f,0.f,0.f,0.f};

  for (int kt = 0; kt < 12; ++kt) {
    __syncthreads();
    int k0 = kt*64;
    #pragma unroll
    for (int c2 = 0; c2 < 4; ++c2) {
      int chunk = c2*4 + w;
      int row = chunk*8 + rloc;
      int g8 = sv ^ (row & 7);
      gl_lds16(Lb + row*NN + k0 + g8*8, As + chunk*512);
      gl_lds16(Rb + row*NN + k0 + g8*8, Bs + chunk*512);
    }
    __syncthreads();
    #pragma unroll
    for (int kk = 0; kk < 64; kk += 32) {
      int k = kk + q*8;
      short8 af[4], bf[4];
      #pragma unroll
      for (int a2 = 0; a2 < 4; ++a2) af[a2] = frag128(As, wi*64 + a2*16 + mm, k);
      #pragma unroll
      for (int b2 = 0; b2 < 4; ++b2) bf[b2] = frag128(Bs, wj*64 + b2*16 + mm, k);
      #pragma unroll
      for (int a2 = 0; a2 < 4; ++a2)
        #pragma unroll
        for (int b2 = 0; b2 < 4; ++b2)
          acc[a2][b2] = mfma_bf(af[a2], bf[b2], acc[a2][b2]);
    }
  }
  u16* Ob = out_ws + (long)d*N2 + (long)(it*128)*NN + jt*128;
  #pragma unroll
  for (int a2 = 0; a2 < 4; ++a2)
    #pragma unroll
    for (int b2 = 0; b2 < 4; ++b2)
      #pragma unroll
      for (int r = 0; r < 4; ++r)
        Ob[(long)(wi*64 + a2*16 + q*4 + r)*NN + wj*64 + b2*16 + mm] = f2b(acc[a2][b2][r]);
}

// ---------------- k3: out-LN over d + gate + @w_out^T ----------------
__global__ __launch_bounds__(256, 4) void k3_out(
    const u16* __restrict__ out_ws, const u16* __restrict__ gate_t,
    const float* __restrict__ onw, const float* __restrict__ onb,
    const u16* __restrict__ wbo, float* __restrict__ out)
{
  __shared__ __align__(16) u16 As[64*128];
  __shared__ float P[8][64];
  const int tid = threadIdx.x, w = tid>>6, l = tid&63;
  const int i = blockIdx.y, jt = blockIdx.x;
  const long base = (long)i*NN + jt*64;       // lane owns column j = base + l

  float v[32]; float s = 0.f, s2 = 0.f;
  const u16* src = out_ws + base + l;
  #pragma unroll
  for (int dd = 0; dd < 32; ++dd) {           // wave w: channels w*32..+31
    float f = b2f(src[(long)(w*32 + dd)*N2]);
    v[dd] = f; s += f; s2 += f*f;
  }
  P[w][l] = s; P[4+w][l] = s2;
  __syncthreads();
  float sum = P[0][l]+P[1][l]+P[2][l]+P[3][l];
  float sq  = P[4][l]+P[5][l]+P[6][l]+P[7][l];
  float mu = sum * 0.0078125f;
  float rs = __builtin_amdgcn_rsqf(sq * 0.0078125f - mu*mu + 1e-5f);

  const u16* gp = gate_t + base + l;          // transposed gate: coalesced reads
  #pragma unroll
  for (int hh = 0; hh < 32; hh += 2) {
    int h = w*32 + hh;
    float g0 = h2f(gp[(long)h*N2]);
    float g1 = h2f(gp[(long)(h+1)*N2]);
    float a0 = ((v[hh]   - mu)*rs*onw[h]   + onb[h])   * g0;
    float a1 = ((v[hh+1] - mu)*rs*onw[h+1] + onb[h+1]) * g1;
    u32 pk = (u32)f2h(a0) | ((u32)f2h(a1)<<16);
    int c = h >> 3, slot = ((c&7)^(l&7)) | (c&8);
    *(u32*)(As + l*128 + slot*8 + (h&7)) = pk;
  }
  __syncthreads();

  const int q = l>>4, mm = l&15;
  f32x4 acc[8];
  #pragma unroll
  for (int b2 = 0; b2 < 8; ++b2) acc[b2] = (f32x4){0.f,0.f,0.f,0.f};
  #pragma unroll
  for (int ks = 0; ks < 4; ++ks) {
    int k = ks*32 + q*8;
    short8 af = frag256(As, w*16 + mm, k);
    #pragma unroll
    for (int b2 = 0; b2 < 8; ++b2)
      acc[b2] = mfma_h(af, fragG(wbo, b2*16 + mm, k), acc[b2]);
  }
  float* ob = out + (base + w*16)*128;
  #pragma unroll
  for (int b2 = 0; b2 < 8; ++b2)
    #pragma unroll
    for (int r = 0; r < 4; ++r)
      ob[(long)(q*4 + r)*128 + b2*16 + mm] = acc[b2][r];
}

extern "C" void kernel_launch(void* const* d_in, const int* in_sizes, int n_in,
                              void* d_out, int out_size, void* d_ws, size_t ws_size,
                              hipStream_t stream) {
  const float* x    = (const float*)d_in[0];
  const float* mask = (const float*)d_in[1];
  const float* nw   = (const float*)d_in[2];
  const float* nb   = (const float*)d_in[3];
  const float* wl   = (const float*)d_in[4];
  const float* wr   = (const float*)d_in[5];
  const float* wlg  = (const float*)d_in[6];
  const float* wrg  = (const float*)d_in[7];
  const float* wog  = (const float*)d_in[8];
  const float* onw  = (const float*)d_in[9];
  const float* onb  = (const float*)d_in[10];
  const float* wo   = (const float*)d_in[11];

  // ws layout: left_t[128][768*768] bf16, right_t bf16, gate_t[128][768*768] fp16,
  //            out_ws[128][768*768] bf16, wbf[6][16][128][8] fp16 (fragment-major)
  if (ws_size < (size_t)4*N2*128*2 + 6*16384*2) return;
  u16* left_t  = (u16*)d_ws;
  u16* right_t = left_t  + (size_t)N2*128;
  u16* gate_t  = right_t + (size_t)N2*128;
  u16* out_ws  = gate_t  + (size_t)N2*128;
  u16* wbf     = out_ws  + (size_t)N2*128;

  k0_cvt<<<48, 256, 0, stream>>>(wlg, wl, wrg, wr, wog, wo, wbf);
  k1_proj<<<4608, 256, 0, stream>>>(x, mask, nw, nb, wbf, left_t, right_t, gate_t);
  k2_gemm<<<4608, 256, 0, stream>>>(left_t, right_t, out_ws);
  k3_out<<<dim3(12, 768), 256, 0, stream>>>(out_ws, gate_t, onw, onb, wbf + 5*16384, (float*)d_out);
}